// Round 18
// baseline (337.208 us; speedup 1.0000x reference)
//
#include <hip/hip_runtime.h>
#include <stdint.h>
#include <math.h>

#define NQ    2562
#define MPTS  16384
#define QPB   2            // queries per block = 2 waves x 1
#define NBQ   1281         // NQ / QPB exactly (no tail)
#define NT    (MPTS / 256) // 64 stream iters per wave (full stream)
#define CAP   320          // stack cap per wave-query: 63 leftover + 256 worst burst

// ---------------------------------------------------------------------------
// Kernel 1: copy inputs [N,3] into output columns 0..2 of [N,15]
// ---------------------------------------------------------------------------
__global__ __launch_bounds__(256)
void passthrough_kernel(const float* __restrict__ inp, float* __restrict__ out) {
    int gid = blockIdx.x * 256 + threadIdx.x;
    if (gid < NQ * 3) {
        int n = gid / 3, c = gid - n * 3;
        out[n * 15 + c] = inp[gid];
    }
}

// key = (x^2sum + y^2sum) - 2*x.y  mirroring numpy association (left-assoc _rn,
// fma dot with pre-doubled query coords).
__device__ __forceinline__ float sqsum3(float y0, float y1, float y2) {
    return __fadd_rn(__fadd_rn(__fmul_rn(y0, y0), __fmul_rn(y1, y1)),
                     __fmul_rn(y2, y2));
}
__device__ __forceinline__ float keyf(float xs, float a2, float b2, float c2,
                                      float y0, float y1, float y2, float ysq) {
    float u = fmaf(c2, y2, fmaf(b2, y1, __fmul_rn(a2, y0)));
    return __fsub_rn(__fadd_rn(xs, ysq), u);
}
__device__ __forceinline__ unsigned long long packkey(float k, int m) {
    uint32_t kb = __float_as_uint(k);
    kb ^= (uint32_t)((int32_t)kb >> 31) | 0x80000000u;  // monotonic total-order map
    return ((unsigned long long)kb << 32) | (unsigned)m;
}
__device__ __forceinline__ float unmapkey(unsigned long long pk) {
    uint32_t kb = (uint32_t)(pk >> 32);
    return __uint_as_float((kb & 0x80000000u) ? (kb ^ 0x80000000u) : ~kb);
}
// popcount of mask over lanes < this lane (v_mbcnt pair)
__device__ __forceinline__ int prefix_lt(unsigned long long m) {
    return __builtin_amdgcn_mbcnt_hi((unsigned)(m >> 32),
           __builtin_amdgcn_mbcnt_lo((unsigned)m, 0u));
}

// 64-lane bitonic sort ascending.
__device__ __forceinline__ unsigned long long sort64(unsigned long long v, int lane) {
#pragma unroll
    for (int k = 2; k <= 64; k <<= 1) {
#pragma unroll
        for (int j = k >> 1; j > 0; j >>= 1) {
            unsigned long long p = __shfl_xor(v, j);
            bool up = ((lane & k) == 0) == ((lane & j) == 0);
            bool sw = up ? (p < v) : (v < p);
            v = sw ? p : v;
        }
    }
    return v;
}

// Fold stack chunks (packed u64, LDS-only) into sorted t16 (LDS). No barriers.
__device__ __forceinline__ float rebuild_q(unsigned long long* t16p,
                                           unsigned long long* S, int& cnt,
                                           int lane, bool fin) {
    int c = cnt;
    int full = c >> 6, rem = c & 63;
    int rounds = full + ((fin && rem) ? 1 : 0);
    unsigned long long v = ~0ULL;
    for (int rd = 0; rd < rounds; ++rd) {
        int i = (rd << 6) + lane;
        unsigned long long pk = (i < c) ? S[i] : ~0ULL;
        pk = sort64(pk, lane);             // asc across lanes
        unsigned long long bsw = __shfl(pk, (31 - lane) & 63);
        v = (lane < 16) ? t16p[lane & 15] : (lane < 32) ? bsw : ~0ULL;
#pragma unroll
        for (int j = 16; j > 0; j >>= 1) {
            unsigned long long p2 = __shfl_xor(v, j);
            bool keepmin = (lane & j) == 0;
            bool less = p2 < v;
            v = (keepmin == less) ? p2 : v;
        }
        if (lane < 16) t16p[lane] = v;
    }
    if (!fin) {
        if (lane < rem) S[lane] = S[(full << 6) + lane];   // disjoint (full>=1)
        cnt = rem;
    } else {
        cnt = 0;
    }
    return unmapkey(__shfl(v, 15));
}

// ---------------------------------------------------------------------------
// Kernel 1b: precompute ysq[pc][m] = ||y||^2 with the exact stream formula
// ---------------------------------------------------------------------------
__global__ __launch_bounds__(256)
void ysq_kernel(const float* __restrict__ pc0, const float* __restrict__ pc1,
                const float* __restrict__ pc2, const float* __restrict__ pc3,
                float* __restrict__ ysq) {
    int gid = blockIdx.x * 256 + threadIdx.x;   // 0 .. 4*MPTS-1
    int pc = gid >> 14, m = gid & (MPTS - 1);
    const float* P = (pc == 0) ? pc0 : (pc == 1) ? pc1 : (pc == 2) ? pc2 : pc3;
    ysq[gid] = sqsum3(P[m], P[MPTS + m], P[2 * MPTS + m]);
}

// ---------------------------------------------------------------------------
// Kernel 2: grid 4*NBQ x 128 (2 waves). Block b: pc = b/NBQ, wave wid owns
// query n = 2*(b%NBQ)+wid, streams ALL 16384 points (4/lane/iter). Main loop
// unrolled x2 with TWO alternating register sets: same 1-tile-ahead latency
// hiding as R16's rotating prefetch but ZERO rotation movs. f32 tau gate +
// LDS stack of packed (key,idx) u64 + batched LDS-only folds. No cross-wave
// traffic, no __syncthreads.
// ---------------------------------------------------------------------------
template <bool USE_YSQ>
__global__ __launch_bounds__(128)
void knn_kernel(const float* __restrict__ inp,
                const float* __restrict__ pc0, const float* __restrict__ pc1,
                const float* __restrict__ pc2, const float* __restrict__ pc3,
                const float* __restrict__ ysq,
                float* __restrict__ out) {
    const int b    = blockIdx.x;
    const int wid  = threadIdx.x >> 6;    // 0..1
    const int lane = threadIdx.x & 63;

    const int pc = b / NBQ;
    const int nb = b - pc * NBQ;
    const float* __restrict__ P = (pc == 0) ? pc0 : (pc == 1) ? pc1
                                : (pc == 2) ? pc2 : pc3;

    __shared__ unsigned long long stk_sh[2][CAP];
    __shared__ unsigned long long t16_sh[2][16];

    if (lane < 16) t16_sh[wid][lane] = ~0ULL;

    // this wave's query
    float A2, B2, C2, XS;
    const int n = QPB * nb + wid;          // always < NQ (2562 = 2*1281)
    {
        float x0 = inp[n * 3 + 0];
        float x1 = inp[n * 3 + 1];
        float x2 = inp[n * 3 + 2];
        A2 = 2.0f * x0;
        B2 = 2.0f * x1;
        C2 = 2.0f * x2;
        XS = sqsum3(x0, x1, x2);
    }
    float tau;
    int   cnt = 0;                         // wave-uniform -> SGPR

    const float* __restrict__ Pl = P + (lane << 2);
    const float* __restrict__ Ql = ysq + pc * MPTS + (lane << 2);

    // push one 256-pt tile (keys in registers); stores packed u64
    auto push_tile = [&](int mofs, float k0, float k1, float k2, float k3) {
        unsigned long long b0 = __ballot(k0 <= tau);
        unsigned long long b1 = __ballot(k1 <= tau);
        unsigned long long b2 = __ballot(k2 <= tau);
        unsigned long long b3 = __ballot(k3 <= tau);
        int pre = prefix_lt(b0) + prefix_lt(b1) + prefix_lt(b2) + prefix_lt(b3);
        int tot = __popcll(b0) + __popcll(b1) + __popcll(b2) + __popcll(b3);
        int pos = cnt + pre;
        unsigned long long* S = stk_sh[wid];
        if (k0 <= tau) S[pos++] = packkey(k0, mofs + 0);
        if (k1 <= tau) S[pos++] = packkey(k1, mofs + 1);
        if (k2 <= tau) S[pos++] = packkey(k2, mofs + 2);
        if (k3 <= tau) S[pos++] = packkey(k3, mofs + 3);
        cnt += tot;
        if (cnt >= 64)                     // headroom: 63 + 256 <= CAP-1
            tau = rebuild_q(t16_sh[wid], S, cnt, lane, false);
    };

// load tile tt into the 4 given float4 registers
#define LOADT(X, Y, Z, Q, tt) do {                                   \
        const int _o = (tt) << 8;                                    \
        X = *(const float4*)(Pl + _o);                               \
        Y = *(const float4*)(Pl + MPTS + _o);                        \
        Z = *(const float4*)(Pl + 2 * MPTS + _o);                    \
        if (USE_YSQ) Q = *(const float4*)(Ql + _o);                  \
    } while (0)

// compute keys for tile tt held in (X,Y,Z,Q) and gate+push
#define PROCT(X, Y, Z, Q, tt) do {                                   \
        const int _mofs = ((tt) << 8) + (lane << 2);                 \
        float _q0, _q1, _q2, _q3;                                    \
        if (USE_YSQ) { _q0 = Q.x; _q1 = Q.y; _q2 = Q.z; _q3 = Q.w; } \
        else {                                                       \
            _q0 = sqsum3(X.x, Y.x, Z.x);                             \
            _q1 = sqsum3(X.y, Y.y, Z.y);                             \
            _q2 = sqsum3(X.z, Y.z, Z.z);                             \
            _q3 = sqsum3(X.w, Y.w, Z.w);                             \
        }                                                            \
        float _k0 = keyf(XS, A2, B2, C2, X.x, Y.x, Z.x, _q0);        \
        float _k1 = keyf(XS, A2, B2, C2, X.y, Y.y, Z.y, _q1);        \
        float _k2 = keyf(XS, A2, B2, C2, X.z, Y.z, Z.z, _q2);        \
        float _k3 = keyf(XS, A2, B2, C2, X.w, Y.w, Z.w, _q3);        \
        float _km = fminf(fminf(_k0, _k1), fminf(_k2, _k3));         \
        if (__ballot(_km <= tau))                                    \
            push_tile(_mofs, _k0, _k1, _k2, _k3);                    \
    } while (0)

    // ---- peeled t=0: warm tau + push ----
    {
        float4 ax, ay, az, aq;
        LOADT(ax, ay, az, aq, 0);
        float q0, q1, q2, q3;
        if (USE_YSQ) { q0 = aq.x; q1 = aq.y; q2 = aq.z; q3 = aq.w; }
        else {
            q0 = sqsum3(ax.x, ay.x, az.x);
            q1 = sqsum3(ax.y, ay.y, az.y);
            q2 = sqsum3(ax.z, ay.z, az.z);
            q3 = sqsum3(ax.w, ay.w, az.w);
        }
        float k0 = keyf(XS, A2, B2, C2, ax.x, ay.x, az.x, q0);
        float k1 = keyf(XS, A2, B2, C2, ax.y, ay.y, az.y, q1);
        float k2 = keyf(XS, A2, B2, C2, ax.z, ay.z, az.z, q2);
        float k3 = keyf(XS, A2, B2, C2, ax.w, ay.w, az.w, q3);
        float km = fminf(fminf(k0, k1), fminf(k2, k3));
        // warm tau0: max over 16 groups (of 4 lanes) of group-mins;
        // >=16 distinct points <= tau0 -> tau0 >= true 16th of these 256.
        float g = km;
        g = fminf(g, __shfl_xor(g, 1));
        g = fminf(g, __shfl_xor(g, 2));
        float m = g;
        m = fmaxf(m, __shfl_xor(m, 4));
        m = fmaxf(m, __shfl_xor(m, 8));
        m = fmaxf(m, __shfl_xor(m, 16));
        m = fmaxf(m, __shfl_xor(m, 32));
        tau = m;
        push_tile(lane << 2, k0, k1, k2, k3);
    }

    // ---- tiles 1..63: unroll x2, alternating register sets, no rotation ----
    {
        float4 AX, AY, AZ, AQ, BX, BY, BZ, BQ;
        LOADT(AX, AY, AZ, AQ, 1);
        LOADT(BX, BY, BZ, BQ, 2);
        for (int t = 1; t <= NT - 3; t += 2) {
            PROCT(AX, AY, AZ, AQ, t);
            LOADT(AX, AY, AZ, AQ, t + 2);            // t+2 <= 63
            PROCT(BX, BY, BZ, BQ, t + 1);
            { const int tn = (t + 3 < NT) ? t + 3 : NT - 1;
              LOADT(BX, BY, BZ, BQ, tn); }           // clamped dup harmless
        }
        PROCT(AX, AY, AZ, AQ, NT - 1);               // tile 63
    }

#undef LOADT
#undef PROCT

    // final fold of remaining stack entries
    if (cnt > 0)
        rebuild_q(t16_sh[wid], stk_sh[wid], cnt, lane, true);

    // tail: t16 sorted ascending; lanes 0..15 gather + mean
    if (lane < 16) {
        unsigned long long v = t16_sh[wid][lane];
        int idx = (int)(unsigned)v;
        float gx = P[idx];
        float gy = P[MPTS + idx];
        float gz = P[2 * MPTS + idx];
#pragma unroll
        for (int off = 8; off > 0; off >>= 1) {
            gx += __shfl_down(gx, off, 16);
            gy += __shfl_down(gy, off, 16);
            gz += __shfl_down(gz, off, 16);
        }
        if (lane == 0) {
            float* o = out + n * 15 + 3 + 3 * pc;
            o[0] = gx * 0.0625f;
            o[1] = gy * 0.0625f;
            o[2] = gz * 0.0625f;
        }
    }
}

extern "C" void kernel_launch(void* const* d_in, const int* in_sizes, int n_in,
                              void* d_out, int out_size, void* d_ws, size_t ws_size,
                              hipStream_t stream) {
    const float* inp = (const float*)d_in[0];
    const float* pc0 = (const float*)d_in[1];
    const float* pc1 = (const float*)d_in[2];
    const float* pc2 = (const float*)d_in[3];
    const float* pc3 = (const float*)d_in[4];
    float* out = (float*)d_out;
    float* ysq = (float*)d_ws;

    hipLaunchKernelGGL(passthrough_kernel, dim3((NQ * 3 + 255) / 256), dim3(256),
                       0, stream, inp, out);

    const bool use_ysq = (ws_size >= (size_t)(4 * MPTS * sizeof(float)));
    if (use_ysq) {
        hipLaunchKernelGGL(ysq_kernel, dim3(4 * MPTS / 256), dim3(256), 0, stream,
                           pc0, pc1, pc2, pc3, ysq);
        hipLaunchKernelGGL((knn_kernel<true>), dim3(4 * NBQ), dim3(128), 0, stream,
                           inp, pc0, pc1, pc2, pc3, ysq, out);
    } else {
        hipLaunchKernelGGL((knn_kernel<false>), dim3(4 * NBQ), dim3(128), 0, stream,
                           inp, pc0, pc1, pc2, pc3, ysq, out);
    }
}

// Round 19
// 104.255 us; speedup vs baseline: 3.2345x; 3.2345x over previous
//
#include <hip/hip_runtime.h>
#include <stdint.h>
#include <math.h>

#define NQ    2562
#define MPTS  16384
#define QPB   2            // queries per block = 2 waves x 1  (residency quantum!)
#define NBQ   1281         // NQ / QPB exactly (no tail)
#define NT    (MPTS / 256) // 64 stream iters per wave (full stream)
#define CAP   320          // stack cap per wave-query: 63 leftover + 256 worst burst

// ---------------------------------------------------------------------------
// Kernel 1: copy inputs [N,3] into output columns 0..2 of [N,15]
// ---------------------------------------------------------------------------
__global__ __launch_bounds__(256)
void passthrough_kernel(const float* __restrict__ inp, float* __restrict__ out) {
    int gid = blockIdx.x * 256 + threadIdx.x;
    if (gid < NQ * 3) {
        int n = gid / 3, c = gid - n * 3;
        out[n * 15 + c] = inp[gid];
    }
}

// key = (x^2sum + y^2sum) - 2*x.y  mirroring numpy association (left-assoc _rn,
// fma dot with pre-doubled query coords).
__device__ __forceinline__ float sqsum3(float y0, float y1, float y2) {
    return __fadd_rn(__fadd_rn(__fmul_rn(y0, y0), __fmul_rn(y1, y1)),
                     __fmul_rn(y2, y2));
}
__device__ __forceinline__ float keyf(float xs, float a2, float b2, float c2,
                                      float y0, float y1, float y2, float ysq) {
    float u = fmaf(c2, y2, fmaf(b2, y1, __fmul_rn(a2, y0)));
    return __fsub_rn(__fadd_rn(xs, ysq), u);
}
__device__ __forceinline__ unsigned long long packkey(float k, int m) {
    uint32_t kb = __float_as_uint(k);
    kb ^= (uint32_t)((int32_t)kb >> 31) | 0x80000000u;  // monotonic total-order map
    return ((unsigned long long)kb << 32) | (unsigned)m;
}
__device__ __forceinline__ float unmapkey(unsigned long long pk) {
    uint32_t kb = (uint32_t)(pk >> 32);
    return __uint_as_float((kb & 0x80000000u) ? (kb ^ 0x80000000u) : ~kb);
}
// popcount of mask over lanes < this lane (v_mbcnt pair)
__device__ __forceinline__ int prefix_lt(unsigned long long m) {
    return __builtin_amdgcn_mbcnt_hi((unsigned)(m >> 32),
           __builtin_amdgcn_mbcnt_lo((unsigned)m, 0u));
}

// 64-lane bitonic sort ascending.
__device__ __forceinline__ unsigned long long sort64(unsigned long long v, int lane) {
#pragma unroll
    for (int k = 2; k <= 64; k <<= 1) {
#pragma unroll
        for (int j = k >> 1; j > 0; j >>= 1) {
            unsigned long long p = __shfl_xor(v, j);
            bool up = ((lane & k) == 0) == ((lane & j) == 0);
            bool sw = up ? (p < v) : (v < p);
            v = sw ? p : v;
        }
    }
    return v;
}

// Fold stack chunks (packed u64, LDS-only) into sorted t16 (LDS). No barriers.
__device__ __forceinline__ float rebuild_q(unsigned long long* t16p,
                                           unsigned long long* S, int& cnt,
                                           int lane, bool fin) {
    int c = cnt;
    int full = c >> 6, rem = c & 63;
    int rounds = full + ((fin && rem) ? 1 : 0);
    unsigned long long v = ~0ULL;
    for (int rd = 0; rd < rounds; ++rd) {
        int i = (rd << 6) + lane;
        unsigned long long pk = (i < c) ? S[i] : ~0ULL;
        pk = sort64(pk, lane);             // asc across lanes
        unsigned long long bsw = __shfl(pk, (31 - lane) & 63);
        v = (lane < 16) ? t16p[lane & 15] : (lane < 32) ? bsw : ~0ULL;
#pragma unroll
        for (int j = 16; j > 0; j >>= 1) {
            unsigned long long p2 = __shfl_xor(v, j);
            bool keepmin = (lane & j) == 0;
            bool less = p2 < v;
            v = (keepmin == less) ? p2 : v;
        }
        if (lane < 16) t16p[lane] = v;
    }
    if (!fin) {
        if (lane < rem) S[lane] = S[(full << 6) + lane];   // disjoint (full>=1)
        cnt = rem;
    } else {
        cnt = 0;
    }
    return unmapkey(__shfl(v, 15));
}

// ---------------------------------------------------------------------------
// Kernel 1b: precompute ysq[pc][m] = ||y||^2 with the exact stream formula
// ---------------------------------------------------------------------------
__global__ __launch_bounds__(256)
void ysq_kernel(const float* __restrict__ pc0, const float* __restrict__ pc1,
                const float* __restrict__ pc2, const float* __restrict__ pc3,
                float* __restrict__ ysq) {
    int gid = blockIdx.x * 256 + threadIdx.x;   // 0 .. 4*MPTS-1
    int pc = gid >> 14, m = gid & (MPTS - 1);
    const float* P = (pc == 0) ? pc0 : (pc == 1) ? pc1 : (pc == 2) ? pc2 : pc3;
    ysq[gid] = sqsum3(P[m], P[MPTS + m], P[2 * MPTS + m]);
}

// ---------------------------------------------------------------------------
// Kernel 2: grid 4*NBQ x 128 (2 waves). Block b: pc = b/NBQ, wave wid owns
// query n = 2*(b%NBQ)+wid, streams ALL 16384 points (4/lane/iter, register
// prefetch). f32 tau gate + LDS stack of packed (key,idx) u64 + batched
// LDS-only folds. No cross-wave traffic, no __syncthreads. 2-wave blocks
// give a fine residency quantum: ~20 blocks/CU, 16 resident -> 1.25 rounds.
// ---------------------------------------------------------------------------
template <bool USE_YSQ>
__global__ __launch_bounds__(128)
void knn_kernel(const float* __restrict__ inp,
                const float* __restrict__ pc0, const float* __restrict__ pc1,
                const float* __restrict__ pc2, const float* __restrict__ pc3,
                const float* __restrict__ ysq,
                float* __restrict__ out) {
    const int b    = blockIdx.x;
    const int wid  = threadIdx.x >> 6;    // 0..1
    const int lane = threadIdx.x & 63;

    const int pc = b / NBQ;
    const int nb = b - pc * NBQ;
    const float* __restrict__ P = (pc == 0) ? pc0 : (pc == 1) ? pc1
                                : (pc == 2) ? pc2 : pc3;

    __shared__ unsigned long long stk_sh[2][CAP];
    __shared__ unsigned long long t16_sh[2][16];

    if (lane < 16) t16_sh[wid][lane] = ~0ULL;

    // this wave's query
    float A2, B2, C2, XS;
    const int n = QPB * nb + wid;          // always < NQ (2562 = 2*1281)
    {
        float x0 = inp[n * 3 + 0];
        float x1 = inp[n * 3 + 1];
        float x2 = inp[n * 3 + 2];
        A2 = 2.0f * x0;
        B2 = 2.0f * x1;
        C2 = 2.0f * x2;
        XS = sqsum3(x0, x1, x2);
    }
    float tau;
    int   cnt = 0;                         // wave-uniform -> SGPR

    const float* __restrict__ Pl = P + (lane << 2);
    const float* __restrict__ Ql = ysq + pc * MPTS + (lane << 2);

    // push one 256-pt tile (keys in registers); stores packed u64
    auto push_tile = [&](int mofs, float k0, float k1, float k2, float k3) {
        unsigned long long b0 = __ballot(k0 <= tau);
        unsigned long long b1 = __ballot(k1 <= tau);
        unsigned long long b2 = __ballot(k2 <= tau);
        unsigned long long b3 = __ballot(k3 <= tau);
        int pre = prefix_lt(b0) + prefix_lt(b1) + prefix_lt(b2) + prefix_lt(b3);
        int tot = __popcll(b0) + __popcll(b1) + __popcll(b2) + __popcll(b3);
        int pos = cnt + pre;
        unsigned long long* S = stk_sh[wid];
        if (k0 <= tau) S[pos++] = packkey(k0, mofs + 0);
        if (k1 <= tau) S[pos++] = packkey(k1, mofs + 1);
        if (k2 <= tau) S[pos++] = packkey(k2, mofs + 2);
        if (k3 <= tau) S[pos++] = packkey(k3, mofs + 3);
        cnt += tot;
        if (cnt >= 64)                     // headroom: 63 + 256 <= CAP-1
            tau = rebuild_q(t16_sh[wid], S, cnt, lane, false);
    };

    // ---- peeled t=0: warm tau + push ----
    {
        float4 ax = *(const float4*)(Pl);
        float4 ay = *(const float4*)(Pl + MPTS);
        float4 az = *(const float4*)(Pl + 2 * MPTS);
        float q0, q1, q2, q3;
        if (USE_YSQ) {
            float4 aq = *(const float4*)(Ql);
            q0 = aq.x; q1 = aq.y; q2 = aq.z; q3 = aq.w;
        } else {
            q0 = sqsum3(ax.x, ay.x, az.x);
            q1 = sqsum3(ax.y, ay.y, az.y);
            q2 = sqsum3(ax.z, ay.z, az.z);
            q3 = sqsum3(ax.w, ay.w, az.w);
        }
        float k0 = keyf(XS, A2, B2, C2, ax.x, ay.x, az.x, q0);
        float k1 = keyf(XS, A2, B2, C2, ax.y, ay.y, az.y, q1);
        float k2 = keyf(XS, A2, B2, C2, ax.z, ay.z, az.z, q2);
        float k3 = keyf(XS, A2, B2, C2, ax.w, ay.w, az.w, q3);
        float km = fminf(fminf(k0, k1), fminf(k2, k3));
        // warm tau0: max over 16 groups (of 4 lanes) of group-mins;
        // >=16 distinct points <= tau0 -> tau0 >= true 16th of these 256.
        float g = km;
        g = fminf(g, __shfl_xor(g, 1));
        g = fminf(g, __shfl_xor(g, 2));
        float m = g;
        m = fmaxf(m, __shfl_xor(m, 4));
        m = fmaxf(m, __shfl_xor(m, 8));
        m = fmaxf(m, __shfl_xor(m, 16));
        m = fmaxf(m, __shfl_xor(m, 32));
        tau = m;
        push_tile(lane << 2, k0, k1, k2, k3);
    }

    // prefetch t=1
    float4 cx = *(const float4*)(Pl + 256);
    float4 cy = *(const float4*)(Pl + MPTS + 256);
    float4 cz = *(const float4*)(Pl + 2 * MPTS + 256);
    float4 cq;
    if (USE_YSQ) cq = *(const float4*)(Ql + 256);

    for (int t = 1; t < NT; ++t) {
        const int tn = (t + 1 < NT) ? t + 1 : t;   // clamped prefetch (dup harmless)
        float4 nx = *(const float4*)(Pl + (tn << 8));
        float4 ny = *(const float4*)(Pl + MPTS + (tn << 8));
        float4 nz = *(const float4*)(Pl + 2 * MPTS + (tn << 8));
        float4 nq;
        if (USE_YSQ) nq = *(const float4*)(Ql + (tn << 8));

        const int mofs = (t << 8) + (lane << 2);
        float q0, q1, q2, q3;
        if (USE_YSQ) {
            q0 = cq.x; q1 = cq.y; q2 = cq.z; q3 = cq.w;
        } else {
            q0 = sqsum3(cx.x, cy.x, cz.x);
            q1 = sqsum3(cx.y, cy.y, cz.y);
            q2 = sqsum3(cx.z, cy.z, cz.z);
            q3 = sqsum3(cx.w, cy.w, cz.w);
        }
        float k0 = keyf(XS, A2, B2, C2, cx.x, cy.x, cz.x, q0);
        float k1 = keyf(XS, A2, B2, C2, cx.y, cy.y, cz.y, q1);
        float k2 = keyf(XS, A2, B2, C2, cx.z, cy.z, cz.z, q2);
        float k3 = keyf(XS, A2, B2, C2, cx.w, cy.w, cz.w, q3);
        float km = fminf(fminf(k0, k1), fminf(k2, k3));
        if (__ballot(km <= tau))
            push_tile(mofs, k0, k1, k2, k3);

        cx = nx; cy = ny; cz = nz;
        if (USE_YSQ) cq = nq;
    }

    // final fold of remaining stack entries
    if (cnt > 0)
        rebuild_q(t16_sh[wid], stk_sh[wid], cnt, lane, true);

    // tail: t16 sorted ascending; lanes 0..15 gather + mean
    if (lane < 16) {
        unsigned long long v = t16_sh[wid][lane];
        int idx = (int)(unsigned)v;
        float gx = P[idx];
        float gy = P[MPTS + idx];
        float gz = P[2 * MPTS + idx];
#pragma unroll
        for (int off = 8; off > 0; off >>= 1) {
            gx += __shfl_down(gx, off, 16);
            gy += __shfl_down(gy, off, 16);
            gz += __shfl_down(gz, off, 16);
        }
        if (lane == 0) {
            float* o = out + n * 15 + 3 + 3 * pc;
            o[0] = gx * 0.0625f;
            o[1] = gy * 0.0625f;
            o[2] = gz * 0.0625f;
        }
    }
}

extern "C" void kernel_launch(void* const* d_in, const int* in_sizes, int n_in,
                              void* d_out, int out_size, void* d_ws, size_t ws_size,
                              hipStream_t stream) {
    const float* inp = (const float*)d_in[0];
    const float* pc0 = (const float*)d_in[1];
    const float* pc1 = (const float*)d_in[2];
    const float* pc2 = (const float*)d_in[3];
    const float* pc3 = (const float*)d_in[4];
    float* out = (float*)d_out;
    float* ysq = (float*)d_ws;

    hipLaunchKernelGGL(passthrough_kernel, dim3((NQ * 3 + 255) / 256), dim3(256),
                       0, stream, inp, out);

    const bool use_ysq = (ws_size >= (size_t)(4 * MPTS * sizeof(float)));
    if (use_ysq) {
        hipLaunchKernelGGL(ysq_kernel, dim3(4 * MPTS / 256), dim3(256), 0, stream,
                           pc0, pc1, pc2, pc3, ysq);
        hipLaunchKernelGGL((knn_kernel<true>), dim3(4 * NBQ), dim3(128), 0, stream,
                           inp, pc0, pc1, pc2, pc3, ysq, out);
    } else {
        hipLaunchKernelGGL((knn_kernel<false>), dim3(4 * NBQ), dim3(128), 0, stream,
                           inp, pc0, pc1, pc2, pc3, ysq, out);
    }
}